// Round 5
// baseline (172.900 us; speedup 1.0000x reference)
//
#include <hip/hip_runtime.h>
#include <hip/hip_bf16.h>

// GlobalFilter: y = irfft2(rfft2(x, ortho) * W, ortho) over axes (1,2)
// == per-channel 14x14 circular convolution with real kernel k_c = ifft2(M_c):
//   k_c[p,q] = (1/196) * sum_{u<14, v<8} c_v * (Wr*cos(th) - Wi*sin(th)),
//   th = 2*pi*(u*p + v*q)/14, c_v = 1 for v in {0,7} else 2.
//
// v4b: no-LDS, no-barrier, 1-wave blocks; lane = channel (coalesced 256B loads);
// 5-slot rolling input-row window + double-buffered k-row, explicit prefetch.
// Grid split A/B: batches 0..63 pure-f32 fmac path, 64..127 pkrtz+fdot2 path
// (both correct; rocprof per-kernel timing measures the f16-dot issue rate).
// (v4 failed compile: cvt_pkrtz returns __fp16x2, needs bit_cast to _Float16x2.)
//
//   kd[m][q] = half2(k[2m][q], k[(2m-1)%14][q])   m=0..6  (built by kernel A)
// Output rows (2g, 2g+1); iteration i consumes input rows 2i, 2i+1, (2i+2)%14
// against k-row m=(g-i)%7:
//   acc0[w] += k_e*x[2i][(w-q)%14] + k_o*x[2i+1][(w-q)%14]
//   acc1[w] += k_e*x[2i+1][(w-q)%14] + k_o*x[(2i+2)%14][(w-q)%14]

typedef _Float16 h2 __attribute__((ext_vector_type(2)));

#define BATCH 128
#define CC 768

// ---------------- Kernel A: build packed spatial kernels kd[7][14][768] (u32=half2) ----
__global__ __launch_bounds__(896) void gf_build_kd(const float* __restrict__ wg,
                                                   unsigned int* __restrict__ kd) {
    __shared__ float ws[112 * 128];        // [uv][cl][ri], pre-scaled by cv/196
    __shared__ float ct[14], st[14];
    int t = threadIdx.x;
    int c0 = blockIdx.x * 64;
    int m  = blockIdx.y;
    if (t < 14) {
        float ang = 6.283185307179586f * (float)t / 14.0f;
        ct[t] = cosf(ang);
        st[t] = sinf(ang);
    }
    #pragma unroll
    for (int j = 0; j < 16; ++j) {
        int f = t + j * 896;               // 0..14335
        int uv = f >> 7;
        int v = uv & 7;
        float scale = (v == 0 || v == 7) ? (1.0f / 196.0f) : (2.0f / 196.0f);
        ws[f] = wg[(size_t)uv * 1536 + (size_t)c0 * 2 + (f & 127)] * scale;
    }
    __syncthreads();

    int q = t >> 6, cl = t & 63;
    int pe = 2 * m;                        // even tap row
    int po = (pe + 13) % 14;               // (2m-1) mod 14
    float ae = 0.f, ao = 0.f;
    int upe = 0, upo = 0;
    #pragma unroll
    for (int u = 0; u < 14; ++u) {
        int vq = 0;
        #pragma unroll
        for (int v = 0; v < 8; ++v) {
            int re = upe + vq; if (re >= 14) re -= 14;
            int ro = upo + vq; if (ro >= 14) ro -= 14;
            float wr = ws[(u * 8 + v) * 128 + cl * 2];
            float wi = ws[(u * 8 + v) * 128 + cl * 2 + 1];
            ae += wr * ct[re]; ae -= wi * st[re];
            ao += wr * ct[ro]; ao -= wi * st[ro];
            vq += q; if (vq >= 14) vq -= 14;
        }
        upe += pe; if (upe >= 14) upe -= 14;
        upo += po; if (upo >= 14) upo -= 14;
    }
    h2 pk; pk.x = (_Float16)ae; pk.y = (_Float16)ao;
    kd[((size_t)m * 14 + q) * CC + c0 + cl] = __builtin_bit_cast(unsigned int, pk);
}

// ---------------- Kernel B: depthwise circular conv, register-pipelined ----------------
// block = 64 threads (1 wave), grid (12 cgroups, 64 batches, 7 g).
template<bool USE_F16>
__global__ __launch_bounds__(64, 2) void gf_conv_t(const float* __restrict__ x,
                                                   const unsigned int* __restrict__ kd,
                                                   float* __restrict__ y, int b_base) {
    int b  = b_base + blockIdx.y;
    int c0 = blockIdx.x * 64;
    int cl = threadIdx.x;                  // lane = channel
    int g  = blockIdx.z;                   // 0..6 -> output rows 2g, 2g+1
    const float* xb = x + (size_t)b * 196 * CC + c0 + cl;
    const unsigned int* kb = kd + c0 + cl;

    float acc0[14], acc1[14];
    #pragma unroll
    for (int w = 0; w < 14; ++w) { acc0[w] = 0.f; acc1[w] = 0.f; }

    float win[5][14];                      // rolling 5-slot row window
    unsigned int kq[2][14];                // double-buffered k-row

    // prologue: rows 0,1,2 -> slots 0,1,2 ; k-row m=g
    #pragma unroll
    for (int w = 0; w < 14; ++w) {
        win[0][w] = xb[(0 * 14 + w) * CC];
        win[1][w] = xb[(1 * 14 + w) * CC];
        win[2][w] = xb[(2 * 14 + w) * CC];
    }
    {
        int m = g;
        #pragma unroll
        for (int q = 0; q < 14; ++q) kq[0][q] = kb[(m * 14 + q) * CC];
    }

    #pragma unroll
    for (int i = 0; i < 7; ++i) {
        // ---- prefetch iteration i+1 (slots disjoint from the 3 consumed below)
        if (i < 6) {
            const int sA = (2 * i + 3) % 5, sB = (2 * i + 4) % 5;
            const int rA = 2 * i + 3, rB = (2 * i + 4) % 14;
            #pragma unroll
            for (int w = 0; w < 14; ++w) {
                win[sA][w] = xb[(rA * 14 + w) * CC];
                win[sB][w] = xb[(rB * 14 + w) * CC];
            }
            int m = g - (i + 1); if (m < 0) m += 7;
            #pragma unroll
            for (int q = 0; q < 14; ++q) kq[(i + 1) & 1][q] = kb[(m * 14 + q) * CC];
        }
        const int s0 = (2 * i) % 5, s1 = (2 * i + 1) % 5, s2 = (2 * i + 2) % 5;

        if constexpr (USE_F16) {
            h2 xev[14], xov[14];
            #pragma unroll
            for (int w = 0; w < 14; ++w) {
                xev[w] = __builtin_bit_cast(h2, __builtin_amdgcn_cvt_pkrtz(win[s0][w], win[s1][w]));
                xov[w] = __builtin_bit_cast(h2, __builtin_amdgcn_cvt_pkrtz(win[s1][w], win[s2][w]));
            }
            #pragma unroll
            for (int q = 0; q < 14; ++q) {
                h2 kv = __builtin_bit_cast(h2, kq[i & 1][q]);
                #pragma unroll
                for (int w = 0; w < 14; ++w) {
                    int src = w - q; if (src < 0) src += 14;
                    acc0[w] = __builtin_amdgcn_fdot2(kv, xev[src], acc0[w], false);
                    acc1[w] = __builtin_amdgcn_fdot2(kv, xov[src], acc1[w], false);
                }
            }
        } else {
            #pragma unroll
            for (int q = 0; q < 14; ++q) {
                h2 kv = __builtin_bit_cast(h2, kq[i & 1][q]);
                float ke = (float)kv.x, ko = (float)kv.y;
                #pragma unroll
                for (int w = 0; w < 14; ++w) {
                    int src = w - q; if (src < 0) src += 14;
                    acc0[w] += ke * win[s0][src];
                    acc0[w] += ko * win[s1][src];
                    acc1[w] += ke * win[s1][src];
                    acc1[w] += ko * win[s2][src];
                }
            }
        }
    }

    float* yb = y + (size_t)b * 196 * CC + c0 + cl;
    int h0 = 2 * g;
    #pragma unroll
    for (int w = 0; w < 14; ++w) {
        yb[(h0 * 14 + w) * CC]       = acc0[w];
        yb[((h0 + 1) * 14 + w) * CC] = acc1[w];
    }
}

extern "C" void kernel_launch(void* const* d_in, const int* in_sizes, int n_in,
                              void* d_out, int out_size, void* d_ws, size_t ws_size,
                              hipStream_t stream) {
    const float* x = (const float*)d_in[0];
    const float* w = (const float*)d_in[1];
    float* y = (float*)d_out;
    unsigned int* kbuf = (unsigned int*)d_ws;   // 98*768*4 = 301,056 B

    gf_build_kd<<<dim3(12, 7), dim3(896), 0, stream>>>(w, kbuf);

    dim3 grid(12, 64, 7);                       // cgroup, batch-half, row-pair
    gf_conv_t<false><<<grid, dim3(64), 0, stream>>>(x, kbuf, y, 0);   // f32 fmac half
    gf_conv_t<true ><<<grid, dim3(64), 0, stream>>>(x, kbuf, y, 64);  // fdot2 half
}